// Round 5
// baseline (273.543 us; speedup 1.0000x reference)
//
#include <hip/hip_runtime.h>

#define S_LEN 2048
#define BATCH_N 2
#define DM 512
#define H_N 8
#define DK_N 64
#define FF_N 2048
#define M_TOK (S_LEN*BATCH_N)  // 4096
#define QSZ (BATCH_N*H_N*S_LEN*DK_N)  // 2097152 elements per q/k/v plane

typedef __attribute__((ext_vector_type(8))) short short8;
typedef __attribute__((ext_vector_type(4))) float f32x4;

__device__ __forceinline__ unsigned short f2b(float f) {
  union { float f; unsigned u; } v; v.f = f;
  unsigned r = v.u + 0x7FFFu + ((v.u >> 16) & 1u);
  return (unsigned short)(r >> 16);
}
__device__ __forceinline__ float b2f(unsigned short u) {
  union { unsigned u; float f; } v; v.u = ((unsigned)u) << 16; return v.f;
}

// async global->LDS, 16B per lane. Dest must be wave-uniform base + lane*16.
// AS casts via integer (generic LDS addr low-32 = LDS offset on AMDGPU).
__device__ __forceinline__ void gl_lds16(const void* g, void* l) {
  __builtin_amdgcn_global_load_lds(
      (__attribute__((address_space(1))) unsigned int*)(unsigned long long)g,
      (__attribute__((address_space(3))) unsigned int*)(unsigned int)(unsigned long long)l,
      16, 0, 0);
}

// ---- f32 -> bf16 cast ----
__global__ void cast_kernel(const float* __restrict__ src,
                            unsigned short* __restrict__ dst, int n) {
  int i = (blockIdx.x * blockDim.x + threadIdx.x) * 4;
  if (i >= n) return;
  float4 v = *(const float4*)(src + i);
  ushort4 o; o.x = f2b(v.x); o.y = f2b(v.y); o.z = f2b(v.z); o.w = f2b(v.w);
  *(ushort4*)(dst + i) = o;
}

// ---- LayerNorm: one row of 512 per block (128 threads) -> bf16 out ----
__global__ __launch_bounds__(128) void ln_kernel(const float* __restrict__ in,
                                                 const float* __restrict__ g,
                                                 const float* __restrict__ b,
                                                 unsigned short* __restrict__ out) {
  int row = blockIdx.x, t = threadIdx.x;
  float4 v = ((const float4*)(in + (size_t)row * DM))[t];
  float s  = v.x + v.y + v.z + v.w;
  float ss = v.x*v.x + v.y*v.y + v.z*v.z + v.w*v.w;
  #pragma unroll
  for (int off = 32; off >= 1; off >>= 1) {
    s  += __shfl_xor(s,  off);
    ss += __shfl_xor(ss, off);
  }
  __shared__ float sh[4];
  if ((t & 63) == 0) { sh[(t>>6)*2] = s; sh[(t>>6)*2+1] = ss; }
  __syncthreads();
  s = sh[0] + sh[2]; ss = sh[1] + sh[3];
  float mean = s * (1.f/512.f);
  float inv  = rsqrtf(ss * (1.f/512.f) - mean*mean + 1e-5f);
  float4 gv = ((const float4*)g)[t];
  float4 bv = ((const float4*)b)[t];
  ushort4 o;
  o.x = f2b((v.x-mean)*inv*gv.x + bv.x);
  o.y = f2b((v.y-mean)*inv*gv.y + bv.y);
  o.z = f2b((v.z-mean)*inv*gv.z + bv.z);
  o.w = f2b((v.w-mean)*inv*gv.w + bv.w);
  ((ushort4*)out)[(size_t)row*128 + t] = o;
}

// ---- 64x64-tile GEMM (kept for N=512): C = A * W^T + bias ----
template<int RELU, int OUTMODE, int RESID>
__global__ __launch_bounds__(256) void gemm_bt(
    const unsigned short* __restrict__ A, const unsigned short* __restrict__ W,
    const float* __restrict__ bias, const float* __restrict__ resid,
    float* __restrict__ Cf, unsigned short* __restrict__ Cb,
    int M, int N, int K)
{
  __shared__ unsigned short As[64*40];
  __shared__ unsigned short Bs[64*40];
  int tid = threadIdx.x;
  int lane = tid & 63, w = tid >> 6;
  int wr = w >> 1, wc = w & 1;
  int bm = blockIdx.y * 64, bn = blockIdx.x * 64;
  f32x4 acc[2][2] = {};
  int lrow = tid >> 2;
  int lcg  = (tid & 3) * 8;
  const size_t aoff = (size_t)(bm + lrow) * K + lcg;
  const size_t boff = (size_t)(bn + lrow) * K + lcg;
  int fr = lane & 15, kg = (lane >> 4) * 8;
  short8 pa = *(const short8*)&A[aoff];
  short8 pb = *(const short8*)&W[boff];
  for (int k0 = 0; k0 < K; k0 += 32) {
    *(short8*)&As[lrow*40 + lcg] = pa;
    *(short8*)&Bs[lrow*40 + lcg] = pb;
    if (k0 + 32 < K) {
      pa = *(const short8*)&A[aoff + k0 + 32];
      pb = *(const short8*)&W[boff + k0 + 32];
    }
    __syncthreads();
    short8 af0 = *(const short8*)&As[(wr*32 +      fr)*40 + kg];
    short8 af1 = *(const short8*)&As[(wr*32 + 16 + fr)*40 + kg];
    short8 bf0 = *(const short8*)&Bs[(wc*32 +      fr)*40 + kg];
    short8 bf1 = *(const short8*)&Bs[(wc*32 + 16 + fr)*40 + kg];
    acc[0][0] = __builtin_amdgcn_mfma_f32_16x16x32_bf16(af0, bf0, acc[0][0], 0,0,0);
    acc[0][1] = __builtin_amdgcn_mfma_f32_16x16x32_bf16(af0, bf1, acc[0][1], 0,0,0);
    acc[1][0] = __builtin_amdgcn_mfma_f32_16x16x32_bf16(af1, bf0, acc[1][0], 0,0,0);
    acc[1][1] = __builtin_amdgcn_mfma_f32_16x16x32_bf16(af1, bf1, acc[1][1], 0,0,0);
    __syncthreads();
  }
  int rbase = (lane >> 4) * 4;
  #pragma unroll
  for (int m = 0; m < 2; m++) {
    #pragma unroll
    for (int n = 0; n < 2; n++) {
      int col = bn + wc*32 + n*16 + (lane & 15);
      float bc = bias[col];
      #pragma unroll
      for (int r = 0; r < 4; r++) {
        int row = bm + wr*32 + m*16 + rbase + r;
        float vv = acc[m][n][r] + bc;
        if (RELU) vv = fmaxf(vv, 0.f);
        if (OUTMODE == 2) {
          int which = col >> 9, hh = (col >> 6) & 7, dd = col & 63;
          size_t idx = ((((size_t)which*BATCH_N + (row & 1))*H_N + hh)*S_LEN + (row >> 1))*DK_N + dd;
          Cb[idx] = f2b(vv);
        } else {
          size_t idx = (size_t)row * N + col;
          if (RESID) vv += resid[idx];
          if (OUTMODE == 1) Cb[idx] = f2b(vv);
          else              Cf[idx] = vv;
        }
      }
    }
  }
}

// ---- 128x128-tile GEMM, global_load_lds staging (m97 structure) ----
// 256 thr / 4 waves; wave = 64x64 out via 4x4 16x16x32 frags. BK=32.
// OUTMODE 1: bf16 row-major (+RELU opt). OUTMODE 2: bf16 qkv scatter.
template<int RELU, int OUTMODE>
__global__ __launch_bounds__(256) void gemm128(
    const unsigned short* __restrict__ A, const unsigned short* __restrict__ W,
    const float* __restrict__ bias, unsigned short* __restrict__ Cb,
    int M, int N, int K)
{
  __shared__ unsigned short As[128*32];
  __shared__ unsigned short Bs[128*32];
  int tid = threadIdx.x, lane = tid & 63, w = tid >> 6;
  int bm = blockIdx.y * 128, bn = blockIdx.x * 128;
  int fr = lane & 15, hi = lane >> 4;
  int kg8 = hi*8, rg = hi*4;
  int wm = (w >> 1) * 64, wn = (w & 1) * 64;
  f32x4 acc[4][4] = {};
  // staging: chunk c (16B): row=c>>2, sub=c&3; thread owns c=tid and c=tid+256
  const unsigned short* ga0 = A + (size_t)(bm +      (tid>>2))*K + (tid&3)*8;
  const unsigned short* ga1 = A + (size_t)(bm + 64 + (tid>>2))*K + (tid&3)*8;
  const unsigned short* gb0 = W + (size_t)(bn +      (tid>>2))*K + (tid&3)*8;
  const unsigned short* gb1 = W + (size_t)(bn + 64 + (tid>>2))*K + (tid&3)*8;
  unsigned short* lA0 = &As[tid*8];
  unsigned short* lA1 = &As[2048 + tid*8];
  unsigned short* lB0 = &Bs[tid*8];
  unsigned short* lB1 = &Bs[2048 + tid*8];
  for (int k0 = 0; k0 < K; k0 += 32) {
    gl_lds16(ga0 + k0, lA0);
    gl_lds16(ga1 + k0, lA1);
    gl_lds16(gb0 + k0, lB0);
    gl_lds16(gb1 + k0, lB1);
    __syncthreads();   // drains vmcnt -> staged data visible
    short8 af[4], bf[4];
    #pragma unroll
    for (int m = 0; m < 4; m++) af[m] = *(const short8*)&As[(wm + m*16 + fr)*32 + kg8];
    #pragma unroll
    for (int n = 0; n < 4; n++) bf[n] = *(const short8*)&Bs[(wn + n*16 + fr)*32 + kg8];
    __builtin_amdgcn_s_setprio(1);
    #pragma unroll
    for (int m = 0; m < 4; m++)
      #pragma unroll
      for (int n = 0; n < 4; n++)
        acc[m][n] = __builtin_amdgcn_mfma_f32_16x16x32_bf16(af[m], bf[n], acc[m][n], 0,0,0);
    __builtin_amdgcn_s_setprio(0);
    __syncthreads();
  }
  #pragma unroll
  for (int m = 0; m < 4; m++) {
    #pragma unroll
    for (int n = 0; n < 4; n++) {
      int col = bn + wn + n*16 + fr;
      float bc = bias[col];
      #pragma unroll
      for (int r = 0; r < 4; r++) {
        int row = bm + wm + m*16 + rg + r;
        float vv = acc[m][n][r] + bc;
        if (RELU) vv = fmaxf(vv, 0.f);
        if (OUTMODE == 2) {
          int which = col >> 9, hh = (col >> 6) & 7, dd = col & 63;
          size_t idx = ((((size_t)which*BATCH_N + (row & 1))*H_N + hh)*S_LEN + (row >> 1))*DK_N + dd;
          Cb[idx] = f2b(vv);
        } else {
          Cb[(size_t)row * N + col] = f2b(vv);
        }
      }
    }
  }
}

// ---- MFMA flash attention, key-range split across blocks ----
// grid 1024 = 64 units x 16 pairs; bid = unit*16 + p keeps pair p on XCD p%8.
// unit -> (qt = unit>>1, kh = unit&1). Block handles 64 q-rows x 1024-key range
// (kh half). No-max softmax -> partials additive; block writes unnormalized
// bf16 O_part[kh] + f32 l_part[kh]; attn_combine merges.
// 8 waves: g=w&3 q-subblock, khalf=w>>2 in-tile 32-key half.
template<int MODE>
__global__ __launch_bounds__(512, 8) void attn_mfma(
    const unsigned short* __restrict__ qg, const unsigned short* __restrict__ kgl,
    const unsigned short* __restrict__ vg, const int* __restrict__ keymask,
    unsigned short* __restrict__ opart, float* __restrict__ lpart)
{
  __shared__ unsigned short SM[4*64*72];   // Qs | Ks | Vt | Ps
  unsigned short* Qs = SM;
  unsigned short* Ks = SM + 64*72;
  unsigned short* Vt = SM + 2*64*72;       // Vt[d][key ^ ((d>>3)<<3)]
  unsigned short* Ps = SM + 3*64*72;
  int tid = threadIdx.x;
  int lane = tid & 63, w = tid >> 6;
  int g = w & 3, khalf = w >> 2;
  int fr = lane & 15, hi = lane >> 4;
  int kg8 = hi * 8, rg = hi * 4;

  int bid = blockIdx.x;
  int p = bid & 15, unit = bid >> 4;
  int qt = unit >> 1, kh = unit & 1;
  int h = p & 7, b = p >> 3;
  const size_t sbase = ((size_t)b*H_N + h)*S_LEN;   // row units

  int kt0 = kh ? 16 : 0;
  int kt1 = (MODE == 0) ? (kh ? qt : (qt < 15 ? qt : 15)) : (kt0 + 15);

  int ro = tid >> 3, c8 = tid & 7;
  *(short8*)&Qs[ro*72 + c8*8] = *(const short8*)&qg[(sbase + (size_t)qt*64 + ro)*DK_N + c8*8];
  // prefetch first tile of this block's range (address always valid)
  short8 rk = *(const short8*)&kgl[(sbase + (size_t)kt0*64 + ro)*DK_N + c8*8];
  short8 rv = *(const short8*)&vg [(sbase + (size_t)kt0*64 + ro)*DK_N + c8*8];
  __syncthreads();
  short8 aq0 = *(const short8*)&Qs[(g*16 + fr)*72 + kg8];
  short8 aq1 = *(const short8*)&Qs[(g*16 + fr)*72 + 32 + kg8];

  f32x4 o_acc[4] = {};
  float lrow[4] = {0.f, 0.f, 0.f, 0.f};
  for (int kt = kt0; kt <= kt1; kt++) {
    __syncthreads();
    {
      *(short8*)&Ks[ro*72 + c8*8] = rk;
      int kwsw = ro ^ (c8 << 3);
      #pragma unroll
      for (int jj = 0; jj < 8; jj++) Vt[(c8*8 + jj)*72 + kwsw] = (unsigned short)rv[jj];
      if (kt < kt1) {
        const size_t gb = (sbase + (size_t)(kt + 1)*64 + ro)*DK_N + c8*8;
        rk = *(const short8*)&kgl[gb];
        rv = *(const short8*)&vg[gb];
      }
    }
    __syncthreads();
    // ---- S = Q K^T ----
    f32x4 s_acc[2] = {};
    __builtin_amdgcn_s_setprio(1);
    #pragma unroll
    for (int n = 0; n < 2; n++) {
      int key = khalf*32 + n*16 + fr;
      short8 bk0 = *(const short8*)&Ks[key*72 + kg8];
      short8 bk1 = *(const short8*)&Ks[key*72 + 32 + kg8];
      s_acc[n] = __builtin_amdgcn_mfma_f32_16x16x32_bf16(aq0, bk0, s_acc[n], 0,0,0);
      s_acc[n] = __builtin_amdgcn_mfma_f32_16x16x32_bf16(aq1, bk1, s_acc[n], 0,0,0);
    }
    __builtin_amdgcn_s_setprio(0);
    // ---- softmax (no max-tracking) ----
    float psum[4] = {0.f, 0.f, 0.f, 0.f};
    #pragma unroll
    for (int n = 0; n < 2; n++) {
      int kl = khalf*32 + n*16 + fr;
      int dead_km = (MODE == 1) ? keymask[b*S_LEN + kt*64 + kl] : 0;
      float pe[4];
      #pragma unroll
      for (int r = 0; r < 4; r++) {
        float sv = s_acc[n][r] * 0.125f;  // 1/sqrt(64)
        float pv = __expf(sv);
        if (MODE == 0) { if (kt == qt && kl > g*16 + rg + r) pv = 0.f; }
        else           { if (dead_km) pv = 0.f; }
        pe[r] = pv;
        psum[r] += pv;
      }
      unsigned u01, u23;
      asm("v_cvt_pk_bf16_f32 %0, %1, %2" : "=v"(u01) : "v"(pe[0]), "v"(pe[1]));
      asm("v_cvt_pk_bf16_f32 %0, %1, %2" : "=v"(u23) : "v"(pe[2]), "v"(pe[3]));
      int rowb = (g*16 + rg)*72 + (kl ^ (hi << 3));
      Ps[rowb]       = (unsigned short)u01;
      Ps[rowb + 72]  = (unsigned short)(u01 >> 16);
      Ps[rowb + 144] = (unsigned short)u23;
      Ps[rowb + 216] = (unsigned short)(u23 >> 16);
    }
    #pragma unroll
    for (int r = 0; r < 4; r++) {
      psum[r] += __shfl_xor(psum[r], 1);
      psum[r] += __shfl_xor(psum[r], 2);
      psum[r] += __shfl_xor(psum[r], 4);
      psum[r] += __shfl_xor(psum[r], 8);
      lrow[r] += psum[r];
    }
    // ---- O += P V ----
    short8 pa = *(const short8*)&Ps[(g*16 + fr)*72 + khalf*32 + (kg8 ^ (((fr >> 2) & 3) << 3))];
    __builtin_amdgcn_s_setprio(1);
    #pragma unroll
    for (int n = 0; n < 4; n++) {
      int d = n*16 + fr;
      int cb = (khalf*32 + kg8) ^ (((d >> 3) & 7) << 3);
      short8 vb = *(const short8*)&Vt[d*72 + cb];
      o_acc[n] = __builtin_amdgcn_mfma_f32_16x16x32_bf16(pa, vb, o_acc[n], 0,0,0);
    }
    __builtin_amdgcn_s_setprio(0);
  }
  // ---- combine in-tile key-halves; write unnormalized partials ----
  __syncthreads();
  float* fb = (float*)SM;
  if (khalf == 1) {
    #pragma unroll
    for (int n = 0; n < 4; n++)
      #pragma unroll
      for (int r = 0; r < 4; r++)
        fb[(g*16 + rg + r)*64 + n*16 + fr] = o_acc[n][r];
    if (fr == 0) {
      #pragma unroll
      for (int r = 0; r < 4; r++) fb[4096 + g*16 + rg + r] = lrow[r];
    }
  }
  __syncthreads();
  if (khalf == 0) {
    const size_t khoff = (size_t)kh * QSZ;
    #pragma unroll
    for (int r = 0; r < 4; r++) {
      float lt = lrow[r] + fb[4096 + g*16 + rg + r];
      int s = qt*64 + g*16 + rg + r;
      if (fr == 0) lpart[kh*32768 + (int)sbase + s] = lt;
      unsigned short* dst = opart + khoff + (sbase + (size_t)s)*DK_N + fr;
      #pragma unroll
      for (int n = 0; n < 4; n++)
        dst[n*16] = f2b(o_acc[n][r] + fb[(g*16 + rg + r)*64 + n*16 + fr]);
    }
  }
}

// ---- merge the two key-range partials: o = (O0+O1)/(l0+l1) ----
__global__ __launch_bounds__(256) void attn_combine(
    const unsigned short* __restrict__ op, const float* __restrict__ lp,
    unsigned short* __restrict__ o)
{
  int t = blockIdx.x*256 + threadIdx.x;
  int f = t*8;
  int col = f & 511, row = f >> 9;
  int h = col >> 6, d = col & 63, s = row >> 1, b = row & 1;
  size_t pr = ((size_t)b*H_N + h)*S_LEN + s;
  size_t base = pr*DK_N + d;
  short8 a = *(const short8*)&op[base];
  short8 c = *(const short8*)&op[(size_t)QSZ + base];
  float l = lp[pr] + lp[32768 + pr];
  float inv = 1.f / l;
  short8 r8;
  #pragma unroll
  for (int i = 0; i < 8; i++) {
    float va = b2f((unsigned short)a[i]) + b2f((unsigned short)c[i]);
    r8[i] = (short)f2b(va * inv);
  }
  *(short8*)&o[(size_t)row*DM + col] = r8;
}

extern "C" void kernel_launch(void* const* d_in, const int* in_sizes, int n_in,
                              void* d_out, int out_size, void* d_ws, size_t ws_size,
                              hipStream_t stream) {
  const float* x       = (const float*)d_in[0];
  const float* memory  = (const float*)d_in[1];
  const int*   memmask = (const int*)d_in[3];
  const float* sa_W = (const float*)d_in[4];
  const float* sa_b = (const float*)d_in[5];
  const float* ca_W = (const float*)d_in[6];
  const float* ca_b = (const float*)d_in[7];
  const float* w1   = (const float*)d_in[8];
  const float* b1   = (const float*)d_in[9];
  const float* w2   = (const float*)d_in[10];
  const float* b2   = (const float*)d_in[11];
  const float* ln_g = (const float*)d_in[12];
  const float* ln_b = (const float*)d_in[13];
  float* out = (float*)d_out;

  char* ws = (char*)d_ws;
  float*          xcur   = (float*)ws;                              // 8 MB
  unsigned short* nx_bf  = (unsigned short*)(ws + (8u<<20));        // 4 MB
  unsigned short* qkv_sa = (unsigned short*)(ws + (12u<<20));       // 12 MB
  unsigned short* q_ca   = (unsigned short*)(ws + (24u<<20));       // 4 MB
  unsigned short* kv_ca  = (unsigned short*)(ws + (28u<<20));       // 8 MB
  unsigned short* o_bf   = (unsigned short*)(ws + (36u<<20));       // 4 MB
  unsigned short* mem_bf = (unsigned short*)(ws + (40u<<20));       // 4 MB
  unsigned short* h_bf   = (unsigned short*)(ws + (44u<<20));       // 16 MB (FFN phase)
  unsigned short* opart  = (unsigned short*)(ws + (44u<<20));       // 8 MB (attn phases)
  float*          lpart  = (float*)(ws + (58u<<20));                // 256 KB (attn phases)
  unsigned short* w_sa   = (unsigned short*)(ws + (60u<<20));       // weights bf16
  unsigned short* w_ca   = w_sa + 4*512*512;
  unsigned short* w_f1   = w_ca + 4*512*512;
  unsigned short* w_f2   = w_f1 + 2048*512;

  cast_kernel<<<1024, 256, 0, stream>>>(sa_W, w_sa, 4*512*512);
  cast_kernel<<<1024, 256, 0, stream>>>(ca_W, w_ca, 4*512*512);
  cast_kernel<<<1024, 256, 0, stream>>>(w1,   w_f1, 2048*512);
  cast_kernel<<<1024, 256, 0, stream>>>(w2,   w_f2, 512*2048);
  cast_kernel<<<2048, 256, 0, stream>>>(memory, mem_bf, M_TOK*512);

  dim3 blk(256);
  dim3 g512 (512/64,  4096/64);
  dim3 q128_1536(1536/128, 4096/128);
  dim3 q128_1024(1024/128, 4096/128);
  dim3 q128_2048(2048/128, 4096/128);

  // ---- self-attention block ----
  ln_kernel<<<4096, 128, 0, stream>>>(x, ln_g, ln_b, nx_bf);
  gemm128<0,2><<<q128_1536, blk, 0, stream>>>(nx_bf, w_sa, sa_b, qkv_sa, 4096, 1536, 512);
  attn_mfma<0><<<1024, 512, 0, stream>>>(qkv_sa, qkv_sa + QSZ, qkv_sa + 2*QSZ, nullptr, opart, lpart);
  attn_combine<<<1024, 256, 0, stream>>>(opart, lpart, o_bf);
  gemm_bt<0,0,1><<<g512, blk, 0, stream>>>(o_bf, w_sa + 3*262144, sa_b + 1536, x, xcur, nullptr, 4096, 512, 512);

  // ---- cross-attention block ----
  ln_kernel<<<4096, 128, 0, stream>>>(xcur, ln_g + 512, ln_b + 512, nx_bf);
  gemm_bt<0,2,0><<<g512,  blk, 0, stream>>>(nx_bf,  w_ca, ca_b, nullptr, nullptr, q_ca, 4096, 512, 512);
  gemm128<0,2><<<q128_1024, blk, 0, stream>>>(mem_bf, w_ca + 262144, ca_b + 512, kv_ca, 4096, 1024, 512);
  attn_mfma<1><<<1024, 512, 0, stream>>>(q_ca, kv_ca, kv_ca + QSZ, memmask, opart, lpart);
  attn_combine<<<1024, 256, 0, stream>>>(opart, lpart, o_bf);
  gemm_bt<0,0,1><<<g512, blk, 0, stream>>>(o_bf, w_ca + 3*262144, ca_b + 1536, xcur, xcur, nullptr, 4096, 512, 512);

  // ---- FFN block ----
  ln_kernel<<<4096, 128, 0, stream>>>(xcur, ln_g + 1024, ln_b + 1024, nx_bf);
  gemm128<1,1><<<q128_2048, blk, 0, stream>>>(nx_bf, w_f1, b1, h_bf, 4096, 2048, 512);
  gemm_bt<0,0,1><<<g512, blk, 0, stream>>>(h_bf, w_f2, b2, xcur, out, nullptr, 4096, 512, 2048);
}

// Round 7
// 212.270 us; speedup vs baseline: 1.2887x; 1.2887x over previous
//
#include <hip/hip_runtime.h>

#define S_LEN 2048
#define BATCH_N 2
#define DM 512
#define H_N 8
#define DK_N 64
#define FF_N 2048
#define M_TOK (S_LEN*BATCH_N)  // 4096
#define QSZ (BATCH_N*H_N*S_LEN*DK_N)  // 2097152 elements per q/k/v plane

typedef __attribute__((ext_vector_type(8))) short short8;
typedef __attribute__((ext_vector_type(4))) float f32x4;
typedef __attribute__((ext_vector_type(16))) float f32x16;
typedef __attribute__((ext_vector_type(4))) unsigned uint4v;

__device__ __forceinline__ unsigned short f2b(float f) {
  union { float f; unsigned u; } v; v.f = f;
  unsigned r = v.u + 0x7FFFu + ((v.u >> 16) & 1u);
  return (unsigned short)(r >> 16);
}
__device__ __forceinline__ float b2f(unsigned short u) {
  union { unsigned u; float f; } v; v.u = ((unsigned)u) << 16; return v.f;
}

// async global->LDS, 16B per lane (dest = wave-uniform base + lane*16).
__device__ __forceinline__ void gl_lds16(const void* g, void* l) {
  __builtin_amdgcn_global_load_lds(
      (__attribute__((address_space(1))) unsigned int*)(unsigned long long)g,
      (__attribute__((address_space(3))) unsigned int*)(unsigned int)(unsigned long long)l,
      16, 0, 0);
}

// ---- f32 -> bf16 cast ----
__global__ void cast_kernel(const float* __restrict__ src,
                            unsigned short* __restrict__ dst, int n) {
  int i = (blockIdx.x * blockDim.x + threadIdx.x) * 4;
  if (i >= n) return;
  float4 v = *(const float4*)(src + i);
  ushort4 o; o.x = f2b(v.x); o.y = f2b(v.y); o.z = f2b(v.z); o.w = f2b(v.w);
  *(ushort4*)(dst + i) = o;
}

// ---- pack key-padding mask into per-tile u64 bitmasks ----
__global__ void maskpack(const int* __restrict__ mm, unsigned long long* __restrict__ bm) {
  int t = threadIdx.x;              // 64 threads: b = t>>5, kt = t&31
  int b = t >> 5, kt = t & 31;
  unsigned long long m = 0ull;
  for (int j = 0; j < 64; j++)
    m |= (unsigned long long)(mm[b*S_LEN + kt*64 + j] != 0) << j;
  bm[b*32 + kt] = m;
}

// ---- LayerNorm: one row of 512 per block (128 threads) -> bf16 out ----
__global__ __launch_bounds__(128) void ln_kernel(const float* __restrict__ in,
                                                 const float* __restrict__ g,
                                                 const float* __restrict__ b,
                                                 unsigned short* __restrict__ out) {
  int row = blockIdx.x, t = threadIdx.x;
  float4 v = ((const float4*)(in + (size_t)row * DM))[t];
  float s  = v.x + v.y + v.z + v.w;
  float ss = v.x*v.x + v.y*v.y + v.z*v.z + v.w*v.w;
  #pragma unroll
  for (int off = 32; off >= 1; off >>= 1) {
    s  += __shfl_xor(s,  off);
    ss += __shfl_xor(ss, off);
  }
  __shared__ float sh[4];
  if ((t & 63) == 0) { sh[(t>>6)*2] = s; sh[(t>>6)*2+1] = ss; }
  __syncthreads();
  s = sh[0] + sh[2]; ss = sh[1] + sh[3];
  float mean = s * (1.f/512.f);
  float inv  = rsqrtf(ss * (1.f/512.f) - mean*mean + 1e-5f);
  float4 gv = ((const float4*)g)[t];
  float4 bv = ((const float4*)b)[t];
  ushort4 o;
  o.x = f2b((v.x-mean)*inv*gv.x + bv.x);
  o.y = f2b((v.y-mean)*inv*gv.y + bv.y);
  o.z = f2b((v.z-mean)*inv*gv.z + bv.z);
  o.w = f2b((v.w-mean)*inv*gv.w + bv.w);
  ((ushort4*)out)[(size_t)row*128 + t] = o;
}

// ---- 64x64-tile GEMM (N=512 cases): C = A * W^T + bias ----
template<int RELU, int OUTMODE, int RESID>
__global__ __launch_bounds__(256) void gemm_bt(
    const unsigned short* __restrict__ A, const unsigned short* __restrict__ W,
    const float* __restrict__ bias, const float* __restrict__ resid,
    float* __restrict__ Cf, unsigned short* __restrict__ Cb,
    int M, int N, int K)
{
  __shared__ unsigned short As[64*40];
  __shared__ unsigned short Bs[64*40];
  int tid = threadIdx.x;
  int lane = tid & 63, w = tid >> 6;
  int wr = w >> 1, wc = w & 1;
  int bm = blockIdx.y * 64, bn = blockIdx.x * 64;
  f32x4 acc[2][2] = {};
  int lrow = tid >> 2;
  int lcg  = (tid & 3) * 8;
  const size_t aoff = (size_t)(bm + lrow) * K + lcg;
  const size_t boff = (size_t)(bn + lrow) * K + lcg;
  int fr = lane & 15, kg = (lane >> 4) * 8;
  short8 pa = *(const short8*)&A[aoff];
  short8 pb = *(const short8*)&W[boff];
  for (int k0 = 0; k0 < K; k0 += 32) {
    *(short8*)&As[lrow*40 + lcg] = pa;
    *(short8*)&Bs[lrow*40 + lcg] = pb;
    if (k0 + 32 < K) {
      pa = *(const short8*)&A[aoff + k0 + 32];
      pb = *(const short8*)&W[boff + k0 + 32];
    }
    __syncthreads();
    short8 af0 = *(const short8*)&As[(wr*32 +      fr)*40 + kg];
    short8 af1 = *(const short8*)&As[(wr*32 + 16 + fr)*40 + kg];
    short8 bf0 = *(const short8*)&Bs[(wc*32 +      fr)*40 + kg];
    short8 bf1 = *(const short8*)&Bs[(wc*32 + 16 + fr)*40 + kg];
    acc[0][0] = __builtin_amdgcn_mfma_f32_16x16x32_bf16(af0, bf0, acc[0][0], 0,0,0);
    acc[0][1] = __builtin_amdgcn_mfma_f32_16x16x32_bf16(af0, bf1, acc[0][1], 0,0,0);
    acc[1][0] = __builtin_amdgcn_mfma_f32_16x16x32_bf16(af1, bf0, acc[1][0], 0,0,0);
    acc[1][1] = __builtin_amdgcn_mfma_f32_16x16x32_bf16(af1, bf1, acc[1][1], 0,0,0);
    __syncthreads();
  }
  int rbase = (lane >> 4) * 4;
  #pragma unroll
  for (int m = 0; m < 2; m++) {
    #pragma unroll
    for (int n = 0; n < 2; n++) {
      int col = bn + wc*32 + n*16 + (lane & 15);
      float bc = bias[col];
      #pragma unroll
      for (int r = 0; r < 4; r++) {
        int row = bm + wr*32 + m*16 + rbase + r;
        float vv = acc[m][n][r] + bc;
        if (RELU) vv = fmaxf(vv, 0.f);
        if (OUTMODE == 2) {
          int which = col >> 9, hh = (col >> 6) & 7, dd = col & 63;
          size_t idx = ((((size_t)which*BATCH_N + (row & 1))*H_N + hh)*S_LEN + (row >> 1))*DK_N + dd;
          Cb[idx] = f2b(vv);
        } else {
          size_t idx = (size_t)row * N + col;
          if (RESID) vv += resid[idx];
          if (OUTMODE == 1) Cb[idx] = f2b(vv);
          else              Cf[idx] = vv;
        }
      }
    }
  }
}

// ---- 128x128-tile GEMM, global_load_lds staging ----
// OUTMODE 1: bf16 row-major (+RELU). OUTMODE 2: qkv scatter; planes >= VSTART
// are written TRANSPOSED ([b][h][d][s]) so attention consumes V^T directly.
template<int RELU, int OUTMODE, int VSTART>
__global__ __launch_bounds__(256) void gemm128(
    const unsigned short* __restrict__ A, const unsigned short* __restrict__ W,
    const float* __restrict__ bias, unsigned short* __restrict__ Cb,
    int M, int N, int K)
{
  __shared__ unsigned short As[128*32];
  __shared__ unsigned short Bs[128*32];
  int tid = threadIdx.x, lane = tid & 63, w = tid >> 6;
  int bm = blockIdx.y * 128, bn = blockIdx.x * 128;
  int fr = lane & 15, hi = lane >> 4;
  int kg8 = hi*8, rg = hi*4;
  int wm = (w >> 1) * 64, wn = (w & 1) * 64;
  f32x4 acc[4][4] = {};
  const unsigned short* ga0 = A + (size_t)(bm +      (tid>>2))*K + (tid&3)*8;
  const unsigned short* ga1 = A + (size_t)(bm + 64 + (tid>>2))*K + (tid&3)*8;
  const unsigned short* gb0 = W + (size_t)(bn +      (tid>>2))*K + (tid&3)*8;
  const unsigned short* gb1 = W + (size_t)(bn + 64 + (tid>>2))*K + (tid&3)*8;
  unsigned short* lA0 = &As[tid*8];
  unsigned short* lA1 = &As[2048 + tid*8];
  unsigned short* lB0 = &Bs[tid*8];
  unsigned short* lB1 = &Bs[2048 + tid*8];
  for (int k0 = 0; k0 < K; k0 += 32) {
    gl_lds16(ga0 + k0, lA0);
    gl_lds16(ga1 + k0, lA1);
    gl_lds16(gb0 + k0, lB0);
    gl_lds16(gb1 + k0, lB1);
    __syncthreads();
    short8 af[4], bf[4];
    #pragma unroll
    for (int m = 0; m < 4; m++) af[m] = *(const short8*)&As[(wm + m*16 + fr)*32 + kg8];
    #pragma unroll
    for (int n = 0; n < 4; n++) bf[n] = *(const short8*)&Bs[(wn + n*16 + fr)*32 + kg8];
    __builtin_amdgcn_s_setprio(1);
    #pragma unroll
    for (int m = 0; m < 4; m++)
      #pragma unroll
      for (int n = 0; n < 4; n++)
        acc[m][n] = __builtin_amdgcn_mfma_f32_16x16x32_bf16(af[m], bf[n], acc[m][n], 0,0,0);
    __builtin_amdgcn_s_setprio(0);
    __syncthreads();
  }
  #pragma unroll
  for (int m = 0; m < 4; m++) {
    #pragma unroll
    for (int n = 0; n < 4; n++) {
      int col = bn + wn + n*16 + fr;
      float bc = bias[col];
      #pragma unroll
      for (int r = 0; r < 4; r++) {
        int row = bm + wm + m*16 + rg + r;
        float vv = acc[m][n][r] + bc;
        if (RELU) vv = fmaxf(vv, 0.f);
        if (OUTMODE == 2) {
          int which = col >> 9, hh = (col >> 6) & 7, dd = col & 63;
          int srow = row >> 1, bb = row & 1;
          size_t idx;
          if (which >= VSTART)
            idx = (size_t)which*QSZ + (((size_t)bb*H_N + hh)*DK_N + dd)*S_LEN + srow;
          else
            idx = (size_t)which*QSZ + (((size_t)bb*H_N + hh)*S_LEN + srow)*DK_N + dd;
          Cb[idx] = f2b(vv);
        } else {
          Cb[(size_t)row * N + col] = f2b(vv);
        }
      }
    }
  }
}

// ---- 32x32-MFMA flash attention, swapped QK^T, in-register P ----
// MODE 0: causal self. MODE 1: key-padding cross (u64 bitmask per tile).
// grid 2048 = (qt 32 x range 4) x 16 pairs; bid = u*16 + p pins pair p to XCD p%8.
// Block: 256 thr = 4 waves (qgp = w&1 -> 32 q-rows; kh2 = w>>1 -> 32-key half).
// Each block covers q-tile qt (64 rows) x key range [range*512, range*512+512).
// No-max softmax -> additive partials; unnormalized O (bf16) + l (f32) per range;
// attn_combine4 merges. K staged [k][d] (stride 72); V consumed from the
// GEMM-transposed plane [b][h][d][s] -> staged [d][k] with b128s (no transpose here).
// P stays in registers: S^T lane holds 16 P-values of one q-column; PV A-frags
// built via v_cvt_pk_bf16_f32 + v_permlane32_swap_b32.
template<int MODE>
__global__ __launch_bounds__(256, 4) void attn2(
    const unsigned short* __restrict__ qg, const unsigned short* __restrict__ kpl,
    const unsigned short* __restrict__ vtpl, const unsigned long long* __restrict__ bm,
    unsigned short* __restrict__ opart, float* __restrict__ lpart)
{
  __shared__ unsigned short SM[2*64*72 + 128];   // Ks | Vt ; tail = lsum; fb aliases front
  unsigned short* Ks = SM;
  unsigned short* Vt = SM + 64*72;
  float* lsum = (float*)(SM + 2*64*72);
  int tid = threadIdx.x;
  int lane = tid & 63, w = tid >> 6;
  int qgp = w & 1, kh2 = w >> 1;
  int l31 = lane & 31, hi5 = lane >> 5;
  int bid = blockIdx.x;
  int p = bid & 15, u = bid >> 4;
  int qt = u >> 2, range = u & 3;
  int h = p & 7, b = p >> 3;
  const size_t sbase = (size_t)(b*H_N + h) * S_LEN;
  int kt0 = range*8, kt1 = kt0 + 7;
  if (MODE == 0) {
    if (kt0 > qt) {   // inactive block: zero partial slice, exit (block-uniform)
      int zr = tid >> 2, zc = (tid & 3) * 16;
      short8 z = {};
      size_t zb = (size_t)range*QSZ + (sbase + (size_t)qt*64 + zr)*DK_N + zc;
      *(short8*)&opart[zb]     = z;
      *(short8*)&opart[zb + 8] = z;
      if (tid < 64) lpart[range*32768 + (int)sbase + qt*64 + tid] = 0.f;
      return;
    }
    if (kt1 > qt) kt1 = qt;
  }
  // Q fragments (B-operand: lane&31 = q-row, elems = d-slice)
  int qrow = qt*64 + qgp*32 + l31;
  short8 qf[4];
  #pragma unroll
  for (int km = 0; km < 4; km++)
    qf[km] = *(const short8*)&qg[(sbase + qrow)*DK_N + km*16 + hi5*8];

  f32x16 oa0 = {}, oa1 = {};
  float lp = 0.f;
  for (int kt = kt0; kt <= kt1; kt++) {
    __syncthreads();
    {
      int sr = tid >> 2, sc = (tid & 3) * 16;
      const unsigned short* kg = &kpl[(sbase + (size_t)kt*64 + sr)*DK_N + sc];
      *(short8*)&Ks[sr*72 + sc]     = *(const short8*)kg;
      *(short8*)&Ks[sr*72 + sc + 8] = *(const short8*)(kg + 8);
      const unsigned short* vg = &vtpl[((size_t)(b*H_N + h)*DK_N + sr)*S_LEN + kt*64 + sc];
      *(short8*)&Vt[sr*72 + sc]     = *(const short8*)vg;
      *(short8*)&Vt[sr*72 + sc + 8] = *(const short8*)(vg + 8);
    }
    __syncthreads();
    // ---- S^T = mfma(K, Q): col = q, rows = k ----
    f32x16 sa = {};
    __builtin_amdgcn_s_setprio(1);
    #pragma unroll
    for (int km = 0; km < 4; km++) {
      short8 kf = *(const short8*)&Ks[(kh2*32 + l31)*72 + km*16 + hi5*8];
      sa = __builtin_amdgcn_mfma_f32_32x32x16_bf16(kf, qf[km], sa, 0, 0, 0);
    }
    __builtin_amdgcn_s_setprio(0);
    // ---- softmax (no max-tracking), mask, in-register ----
    unsigned mlo = 0;
    if (MODE == 1) {
      unsigned long long mw = bm[b*32 + kt];
      mlo = (unsigned)(mw >> (kh2*32 + 4*hi5));
    }
    float pv[16];
    float psum = 0.f;
    int qv = qgp*32 + l31;
    #pragma unroll
    for (int r = 0; r < 16; r++) {
      const int pos = (r & 3) + 8*(r >> 2);
      float e = __expf(sa[r] * 0.125f);
      bool dead;
      if (MODE == 0) dead = (kt == qt) && (kh2*32 + 4*hi5 + pos > qv);
      else           dead = ((mlo >> pos) & 1u) != 0u;
      e = dead ? 0.f : e;
      pv[r] = e;
      psum += e;
    }
    lp += psum;
    // ---- P -> bf16 A-fragments via cvt_pk + permlane32_swap ----
    // swap semantics: vdst.hi <-> vsrc.lo. With (vdst=pk[j], vsrc=pk[j+2]):
    //   pk[j]   -> {lo: pk[j]@lo,  hi: pk[j+2]@lo} = fragment word j
    //   pk[j+2] -> {lo: pk[j]@hi,  hi: pk[j+2]@hi} = fragment word j+2
    unsigned pk[8];
    #pragma unroll
    for (int i = 0; i < 8; i++)
      asm("v_cvt_pk_bf16_f32 %0, %1, %2" : "=v"(pk[i]) : "v"(pv[2*i]), "v"(pv[2*i+1]));
    asm("v_permlane32_swap_b32 %0, %1" : "+v"(pk[0]), "+v"(pk[2]));
    asm("v_permlane32_swap_b32 %0, %1" : "+v"(pk[1]), "+v"(pk[3]));
    asm("v_permlane32_swap_b32 %0, %1" : "+v"(pk[4]), "+v"(pk[6]));
    asm("v_permlane32_swap_b32 %0, %1" : "+v"(pk[5]), "+v"(pk[7]));
    uint4v f0v, f1v;
    f0v.x = pk[0]; f0v.y = pk[1]; f0v.z = pk[2]; f0v.w = pk[3];
    f1v.x = pk[4]; f1v.y = pk[5]; f1v.z = pk[6]; f1v.w = pk[7];
    short8 pf0 = *(short8*)&f0v;
    short8 pf1 = *(short8*)&f1v;
    // ---- O += P V: mfma(P, Vt): col = d, rows = q ----
    __builtin_amdgcn_s_setprio(1);
    {
      short8 v00 = *(const short8*)&Vt[(     l31)*72 + kh2*32 +      hi5*8];
      short8 v01 = *(const short8*)&Vt[(     l31)*72 + kh2*32 + 16 + hi5*8];
      oa0 = __builtin_amdgcn_mfma_f32_32x32x16_bf16(pf0, v00, oa0, 0, 0, 0);
      oa0 = __builtin_amdgcn_mfma_f32_32x32x16_bf16(pf1, v01, oa0, 0, 0, 0);
      short8 v10 = *(const short8*)&Vt[(32 + l31)*72 + kh2*32 +      hi5*8];
      short8 v11 = *(const short8*)&Vt[(32 + l31)*72 + kh2*32 + 16 + hi5*8];
      oa1 = __builtin_amdgcn_mfma_f32_32x32x16_bf16(pf0, v10, oa1, 0, 0, 0);
      oa1 = __builtin_amdgcn_mfma_f32_32x32x16_bf16(pf1, v11, oa1, 0, 0, 0);
    }
    __builtin_amdgcn_s_setprio(0);
  }
  // ---- epilogue: combine kh2 halves via LDS, write unnormalized partials ----
  float lptot = lp + __shfl_xor(lp, 32);
  float* fb = (float*)SM;   // 64x64 f32, aliases Ks/Vt (done reading)
  __syncthreads();
  if (kh2 == 1) {
    #pragma unroll
    for (int r = 0; r < 16; r++) {
      const int pos = (r & 3) + 8*(r >> 2);
      int qr = qgp*32 + pos + 4*hi5;
      fb[qr*64 + l31]      = oa0[r];
      fb[qr*64 + 32 + l31] = oa1[r];
    }
    if (lane < 32) lsum[qgp*32 + l31] = lptot;
  }
  __syncthreads();
  if (kh2 == 0) {
    if (lane < 32)
      lpart[range*32768 + (int)sbase + qt*64 + qgp*32 + l31] = lptot + lsum[qgp*32 + l31];
    #pragma unroll
    for (int r = 0; r < 16; r++) {
      const int pos = (r & 3) + 8*(r >> 2);
      int qr = qgp*32 + pos + 4*hi5;
      size_t obase = (size_t)range*QSZ + (sbase + (size_t)qt*64 + qr)*DK_N;
      opart[obase + l31]      = f2b(oa0[r] + fb[qr*64 + l31]);
      opart[obase + 32 + l31] = f2b(oa1[r] + fb[qr*64 + 32 + l31]);
    }
  }
}

// ---- merge the four key-range partials: o = sum(O_r) / sum(l_r) ----
__global__ __launch_bounds__(256) void attn_combine4(
    const unsigned short* __restrict__ op, const float* __restrict__ lp,
    unsigned short* __restrict__ o)
{
  int t = blockIdx.x*256 + threadIdx.x;
  int f = t*8;
  int col = f & 511, row = f >> 9;
  int h = col >> 6, d = col & 63, s = row >> 1, b = row & 1;
  size_t pr = ((size_t)b*H_N + h)*S_LEN + s;
  size_t base = pr*DK_N + d;
  float acc[8] = {0.f,0.f,0.f,0.f,0.f,0.f,0.f,0.f};
  float l = 0.f;
  #pragma unroll
  for (int r = 0; r < 4; r++) {
    short8 a = *(const short8*)&op[(size_t)r*QSZ + base];
    #pragma unroll
    for (int i = 0; i < 8; i++) acc[i] += b2f((unsigned short)a[i]);
    l += lp[r*32768 + (int)pr];
  }
  float inv = 1.f / l;
  short8 r8;
  #pragma unroll
  for (int i = 0; i < 8; i++) r8[i] = (short)f2b(acc[i] * inv);
  *(short8*)&o[(size_t)row*DM + col] = r8;
}

extern "C" void kernel_launch(void* const* d_in, const int* in_sizes, int n_in,
                              void* d_out, int out_size, void* d_ws, size_t ws_size,
                              hipStream_t stream) {
  const float* x       = (const float*)d_in[0];
  const float* memory  = (const float*)d_in[1];
  const int*   memmask = (const int*)d_in[3];
  const float* sa_W = (const float*)d_in[4];
  const float* sa_b = (const float*)d_in[5];
  const float* ca_W = (const float*)d_in[6];
  const float* ca_b = (const float*)d_in[7];
  const float* w1   = (const float*)d_in[8];
  const float* b1   = (const float*)d_in[9];
  const float* w2   = (const float*)d_in[10];
  const float* b2   = (const float*)d_in[11];
  const float* ln_g = (const float*)d_in[12];
  const float* ln_b = (const float*)d_in[13];
  float* out = (float*)d_out;

  char* ws = (char*)d_ws;
  float*          xcur   = (float*)ws;                              // 0..8 MB
  unsigned short* nx_bf  = (unsigned short*)(ws + (8u<<20));        // 8..12 MB
  unsigned short* qkv_sa = (unsigned short*)(ws + (12u<<20));       // 12..24 MB
  unsigned short* q_ca   = (unsigned short*)(ws + (24u<<20));       // 24..28 MB
  unsigned short* kv_ca  = (unsigned short*)(ws + (28u<<20));       // 28..36 MB
  unsigned short* o_bf   = (unsigned short*)(ws + (36u<<20));       // 36..40 MB
  unsigned short* mem_bf = (unsigned short*)(ws + (40u<<20));       // 40..44 MB
  unsigned short* h_bf   = (unsigned short*)(ws + (44u<<20));       // 44..60 MB (FFN)
  unsigned short* opart  = (unsigned short*)(ws + (44u<<20));       // 44..60 MB (attn)
  float*          lpart  = (float*)(ws + (60u<<20));                // 60..60.5 MB
  unsigned long long* bmsk = (unsigned long long*)(ws + (60u<<20) + (1u<<19)); // 512 B
  unsigned short* w_sa   = (unsigned short*)(ws + (61u<<20));       // weights bf16
  unsigned short* w_ca   = w_sa + 4*512*512;
  unsigned short* w_f1   = w_ca + 4*512*512;
  unsigned short* w_f2   = w_f1 + 2048*512;

  cast_kernel<<<1024, 256, 0, stream>>>(sa_W, w_sa, 4*512*512);
  cast_kernel<<<1024, 256, 0, stream>>>(ca_W, w_ca, 4*512*512);
  cast_kernel<<<1024, 256, 0, stream>>>(w1,   w_f1, 2048*512);
  cast_kernel<<<1024, 256, 0, stream>>>(w2,   w_f2, 512*2048);
  cast_kernel<<<2048, 256, 0, stream>>>(memory, mem_bf, M_TOK*512);
  maskpack<<<1, 64, 0, stream>>>(memmask, bmsk);

  dim3 blk(256);
  dim3 g512 (512/64,  4096/64);
  dim3 q128_1536(1536/128, 4096/128);
  dim3 q128_1024(1024/128, 4096/128);
  dim3 q128_2048(2048/128, 4096/128);

  // ---- self-attention block ----
  ln_kernel<<<4096, 128, 0, stream>>>(x, ln_g, ln_b, nx_bf);
  gemm128<0,2,2><<<q128_1536, blk, 0, stream>>>(nx_bf, w_sa, sa_b, qkv_sa, 4096, 1536, 512);
  attn2<0><<<2048, 256, 0, stream>>>(qkv_sa, qkv_sa + QSZ, qkv_sa + 2*QSZ, nullptr, opart, lpart);
  attn_combine4<<<1024, 256, 0, stream>>>(opart, lpart, o_bf);
  gemm_bt<0,0,1><<<g512, blk, 0, stream>>>(o_bf, w_sa + 3*262144, sa_b + 1536, x, xcur, nullptr, 4096, 512, 512);

  // ---- cross-attention block ----
  ln_kernel<<<4096, 128, 0, stream>>>(xcur, ln_g + 512, ln_b + 512, nx_bf);
  gemm_bt<0,2,0><<<g512, blk, 0, stream>>>(nx_bf, w_ca, ca_b, nullptr, nullptr, q_ca, 4096, 512, 512);
  gemm128<0,2,1><<<q128_1024, blk, 0, stream>>>(mem_bf, w_ca + 262144, ca_b + 512, kv_ca, 4096, 1024, 512);
  attn2<1><<<2048, 256, 0, stream>>>(q_ca, kv_ca, kv_ca + QSZ, bmsk, opart, lpart);
  attn_combine4<<<1024, 256, 0, stream>>>(opart, lpart, o_bf);
  gemm_bt<0,0,1><<<g512, blk, 0, stream>>>(o_bf, w_ca + 3*262144, ca_b + 1536, xcur, xcur, nullptr, 4096, 512, 512);

  // ---- FFN block ----
  ln_kernel<<<4096, 128, 0, stream>>>(xcur, ln_g + 1024, ln_b + 1024, nx_bf);
  gemm128<1,1,0><<<q128_2048, blk, 0, stream>>>(nx_bf, w_f1, b1, h_bf, 4096, 2048, 512);
  gemm_bt<0,0,1><<<g512, blk, 0, stream>>>(h_bf, w_f2, b2, xcur, out, nullptr, 4096, 512, 2048);
}